// Round 1
// baseline (5638.839 us; speedup 1.0000x reference)
//
#include <hip/hip_runtime.h>

#define N_NODES 50000
#define N_EDGES 800000
#define M_IN 512
#define H_OUT 512

// ---------------------------------------------------------------------------
// K1: Y[dst,:] += X[src,:] * val   — one 64-lane wave per edge.
// Each lane handles 8 floats (2x float4), coalesced reads of X[src] row.
// 512 fp32 atomicAdds per edge into Y.
// ---------------------------------------------------------------------------
__global__ __launch_bounds__(256) void scatter_edges_kernel(
    const float* __restrict__ X,
    const int*   __restrict__ esrc,
    const int*   __restrict__ edst,
    const float* __restrict__ eval,
    float*       __restrict__ Y)
{
    const int wave = blockIdx.x * 4 + (threadIdx.x >> 6);
    const int lane = threadIdx.x & 63;
    if (wave >= N_EDGES) return;

    const int   s = esrc[wave];
    const int   d = edst[wave];
    const float v = eval[wave];

    const float4* xs = (const float4*)(X + (size_t)s * M_IN);
    float*        yd = Y + (size_t)d * M_IN;

#pragma unroll
    for (int r = 0; r < 2; ++r) {
        const int idx4 = r * 64 + lane;      // float4 index 0..127, coalesced
        const float4 x = xs[idx4];
        const int base = idx4 * 4;
        atomicAdd(yd + base + 0, x.x * v);
        atomicAdd(yd + base + 1, x.y * v);
        atomicAdd(yd + base + 2, x.z * v);
        atomicAdd(yd + base + 3, x.w * v);
    }
}

// ---------------------------------------------------------------------------
// K2: out = relu(Y @ W)  — fp32 tiled GEMM (no fp32 MFMA on CDNA4).
// 64x64 tile, BK=16, 256 threads, 4x4 micro-tile per thread.
// ---------------------------------------------------------------------------
#define BM 64
#define BN 64
#define BK 16
#define APAD 4   // keep rows 16B-aligned for float4 LDS access
#define BPAD 4

__global__ __launch_bounds__(256) void gemm_relu_kernel(
    const float* __restrict__ Y,
    const float* __restrict__ W,
    float*       __restrict__ out)
{
    __shared__ float As[BK][BM + APAD];  // As[k][m] (A tile stored transposed)
    __shared__ float Bs[BK][BN + BPAD];  // Bs[k][n]

    const int row0 = blockIdx.x * BM;
    const int col0 = blockIdx.y * BN;
    const int tid  = threadIdx.x;
    const int tx   = tid & 15;   // col group 0..15
    const int ty   = tid >> 4;   // row group 0..15

    // A-load mapping: 64 rows x 16 k, each thread one float4
    const int a_row  = tid >> 2;        // 0..63
    const int a_col4 = (tid & 3) * 4;   // 0,4,8,12
    // B-load mapping: 16 k-rows x 64 cols, each thread one float4
    const int b_row  = tid >> 4;        // 0..15
    const int b_col4 = (tid & 15) * 4;  // 0..60

    float acc[4][4] = {};

    for (int k0 = 0; k0 < M_IN; k0 += BK) {
        // stage A (with row guard for the 50000 tail)
        float4 a = make_float4(0.f, 0.f, 0.f, 0.f);
        const int gr = row0 + a_row;
        if (gr < N_NODES)
            a = *(const float4*)(Y + (size_t)gr * M_IN + k0 + a_col4);
        As[a_col4 + 0][a_row] = a.x;
        As[a_col4 + 1][a_row] = a.y;
        As[a_col4 + 2][a_row] = a.z;
        As[a_col4 + 3][a_row] = a.w;

        // stage B
        const float4 b = *(const float4*)(W + (size_t)(k0 + b_row) * H_OUT + col0 + b_col4);
        *(float4*)&Bs[b_row][b_col4] = b;

        __syncthreads();

#pragma unroll
        for (int k = 0; k < BK; ++k) {
            float av[4], bv[4];
            *(float4*)av = *(const float4*)&As[k][ty * 4];
            *(float4*)bv = *(const float4*)&Bs[k][tx * 4];
#pragma unroll
            for (int i = 0; i < 4; ++i)
#pragma unroll
                for (int j = 0; j < 4; ++j)
                    acc[i][j] += av[i] * bv[j];
        }
        __syncthreads();
    }

    // epilogue: fused ReLU, float4 stores
#pragma unroll
    for (int i = 0; i < 4; ++i) {
        const int r = row0 + ty * 4 + i;
        if (r < N_NODES) {
            float4 o;
            o.x = fmaxf(acc[i][0], 0.f);
            o.y = fmaxf(acc[i][1], 0.f);
            o.z = fmaxf(acc[i][2], 0.f);
            o.w = fmaxf(acc[i][3], 0.f);
            *(float4*)(out + (size_t)r * H_OUT + col0 + tx * 4) = o;
        }
    }
}

extern "C" void kernel_launch(void* const* d_in, const int* in_sizes, int n_in,
                              void* d_out, int out_size, void* d_ws, size_t ws_size,
                              hipStream_t stream) {
    const float* X    = (const float*)d_in[0];
    const float* W    = (const float*)d_in[1];
    const int*   esrc = (const int*)d_in[2];
    const int*   edst = (const int*)d_in[3];
    const float* eval = (const float*)d_in[4];
    float* out = (float*)d_out;
    float* Y   = (float*)d_ws;   // [N_NODES, M_IN] fp32 scratch = 102.4 MB

    hipMemsetAsync(Y, 0, (size_t)N_NODES * M_IN * sizeof(float), stream);

    scatter_edges_kernel<<<(N_EDGES + 3) / 4, 256, 0, stream>>>(X, esrc, edst, eval, Y);

    dim3 grid((N_NODES + BM - 1) / BM, H_OUT / BN);
    gemm_relu_kernel<<<grid, 256, 0, stream>>>(Y, W, out);
}

// Round 2
// 787.099 us; speedup vs baseline: 7.1641x; 7.1641x over previous
//
#include <hip/hip_runtime.h>

#define N_NODES 50000
#define N_EDGES 800000
#define M_IN 512
#define H_OUT 512

// ---------------------------------------------------------------------------
// CSR build: counts/cursor [N], offsets [N+1], srcs [E], vals [E] in d_ws
// ---------------------------------------------------------------------------
__global__ __launch_bounds__(256) void hist_kernel(
    const int* __restrict__ edst, int* __restrict__ counts)
{
    const int e = blockIdx.x * 256 + threadIdx.x;
    if (e < N_EDGES) atomicAdd(&counts[edst[e]], 1);
}

// single-block exclusive scan over 50000 counts -> offsets[0..N]
__global__ __launch_bounds__(256) void scan_kernel(
    const int* __restrict__ counts, int* __restrict__ offs)
{
    __shared__ int psum[256];
    const int tid = threadIdx.x;
    const int CH  = (N_NODES + 255) / 256;            // 196
    const int b   = tid * CH;
    const int e   = min(b + CH, N_NODES);
    int s = 0;
    for (int i = b; i < e; ++i) s += counts[i];
    psum[tid] = s;
    __syncthreads();
    if (tid == 0) {
        int run = 0;
        for (int i = 0; i < 256; ++i) { int t = psum[i]; psum[i] = run; run += t; }
    }
    __syncthreads();
    int run = psum[tid];
    for (int i = b; i < e; ++i) { offs[i] = run; run += counts[i]; }
    if (e == N_NODES) offs[N_NODES] = run;
}

__global__ __launch_bounds__(256) void build_kernel(
    const int* __restrict__ esrc, const int* __restrict__ edst,
    const float* __restrict__ eval,
    const int* __restrict__ offs, int* __restrict__ cursor,
    int* __restrict__ srcs, float* __restrict__ vals)
{
    const int e = blockIdx.x * 256 + threadIdx.x;
    if (e >= N_EDGES) return;
    const int d   = edst[e];
    const int pos = offs[d] + atomicAdd(&cursor[d], 1);
    srcs[pos] = esrc[e];
    vals[pos] = eval[e];
}

// ---------------------------------------------------------------------------
// Gather: one 64-lane wave per dst node. Row accumulated in registers
// (2x float4 per lane = 512 floats per wave), written once — no atomics.
// X is L3-resident (102.4 MB < 256 MB Infinity Cache).
// ---------------------------------------------------------------------------
__global__ __launch_bounds__(256) void gather_kernel(
    const float* __restrict__ X,
    const int*   __restrict__ offs,
    const int*   __restrict__ srcs,
    const float* __restrict__ vals,
    float*       __restrict__ Y)
{
    const int node = blockIdx.x * 4 + (threadIdx.x >> 6);
    const int lane = threadIdx.x & 63;
    if (node >= N_NODES) return;

    const int beg = offs[node];
    const int end = offs[node + 1];

    float4 a0 = make_float4(0.f, 0.f, 0.f, 0.f);
    float4 a1 = make_float4(0.f, 0.f, 0.f, 0.f);

    int e = beg;
    // 2-edge unroll for ILP (independent row loads in flight)
    for (; e + 1 < end; e += 2) {
        const int   s0 = srcs[e],     s1 = srcs[e + 1];
        const float v0 = vals[e],     v1 = vals[e + 1];
        const float4* x0 = (const float4*)(X + (size_t)s0 * M_IN);
        const float4* x1 = (const float4*)(X + (size_t)s1 * M_IN);
        const float4 p0 = x0[lane], p1 = x0[64 + lane];
        const float4 q0 = x1[lane], q1 = x1[64 + lane];
        a0.x += p0.x * v0; a0.y += p0.y * v0; a0.z += p0.z * v0; a0.w += p0.w * v0;
        a1.x += p1.x * v0; a1.y += p1.y * v0; a1.z += p1.z * v0; a1.w += p1.w * v0;
        a0.x += q0.x * v1; a0.y += q0.y * v1; a0.z += q0.z * v1; a0.w += q0.w * v1;
        a1.x += q1.x * v1; a1.y += q1.y * v1; a1.z += q1.z * v1; a1.w += q1.w * v1;
    }
    if (e < end) {
        const int   s0 = srcs[e];
        const float v0 = vals[e];
        const float4* x0 = (const float4*)(X + (size_t)s0 * M_IN);
        const float4 p0 = x0[lane], p1 = x0[64 + lane];
        a0.x += p0.x * v0; a0.y += p0.y * v0; a0.z += p0.z * v0; a0.w += p0.w * v0;
        a1.x += p1.x * v0; a1.y += p1.y * v0; a1.z += p1.z * v0; a1.w += p1.w * v0;
    }

    float4* yd = (float4*)(Y + (size_t)node * M_IN);
    yd[lane]      = a0;
    yd[64 + lane] = a1;
}

// ---------------------------------------------------------------------------
// out = relu(Y @ W) — fp32 tiled GEMM (unchanged from round 1)
// ---------------------------------------------------------------------------
#define BM 64
#define BN 64
#define BK 16
#define APAD 4
#define BPAD 4

__global__ __launch_bounds__(256) void gemm_relu_kernel(
    const float* __restrict__ Y,
    const float* __restrict__ W,
    float*       __restrict__ out)
{
    __shared__ float As[BK][BM + APAD];
    __shared__ float Bs[BK][BN + BPAD];

    const int row0 = blockIdx.x * BM;
    const int col0 = blockIdx.y * BN;
    const int tid  = threadIdx.x;
    const int tx   = tid & 15;
    const int ty   = tid >> 4;

    const int a_row  = tid >> 2;
    const int a_col4 = (tid & 3) * 4;
    const int b_row  = tid >> 4;
    const int b_col4 = (tid & 15) * 4;

    float acc[4][4] = {};

    for (int k0 = 0; k0 < M_IN; k0 += BK) {
        float4 a = make_float4(0.f, 0.f, 0.f, 0.f);
        const int gr = row0 + a_row;
        if (gr < N_NODES)
            a = *(const float4*)(Y + (size_t)gr * M_IN + k0 + a_col4);
        As[a_col4 + 0][a_row] = a.x;
        As[a_col4 + 1][a_row] = a.y;
        As[a_col4 + 2][a_row] = a.z;
        As[a_col4 + 3][a_row] = a.w;

        const float4 b = *(const float4*)(W + (size_t)(k0 + b_row) * H_OUT + col0 + b_col4);
        *(float4*)&Bs[b_row][b_col4] = b;

        __syncthreads();

#pragma unroll
        for (int k = 0; k < BK; ++k) {
            float av[4], bv[4];
            *(float4*)av = *(const float4*)&As[k][ty * 4];
            *(float4*)bv = *(const float4*)&Bs[k][tx * 4];
#pragma unroll
            for (int i = 0; i < 4; ++i)
#pragma unroll
                for (int j = 0; j < 4; ++j)
                    acc[i][j] += av[i] * bv[j];
        }
        __syncthreads();
    }

#pragma unroll
    for (int i = 0; i < 4; ++i) {
        const int r = row0 + ty * 4 + i;
        if (r < N_NODES) {
            float4 o;
            o.x = fmaxf(acc[i][0], 0.f);
            o.y = fmaxf(acc[i][1], 0.f);
            o.z = fmaxf(acc[i][2], 0.f);
            o.w = fmaxf(acc[i][3], 0.f);
            *(float4*)(out + (size_t)r * H_OUT + col0 + tx * 4) = o;
        }
    }
}

extern "C" void kernel_launch(void* const* d_in, const int* in_sizes, int n_in,
                              void* d_out, int out_size, void* d_ws, size_t ws_size,
                              hipStream_t stream) {
    const float* X    = (const float*)d_in[0];
    const float* W    = (const float*)d_in[1];
    const int*   esrc = (const int*)d_in[2];
    const int*   edst = (const int*)d_in[3];
    const float* eval = (const float*)d_in[4];
    float* out = (float*)d_out;

    // workspace layout
    float* Y      = (float*)d_ws;                       // 25,600,000 f32 (102.4 MB)
    int*   offs   = (int*)(Y + (size_t)N_NODES * M_IN); // 50001
    int*   cursor = offs + (N_NODES + 1);               // 50000 (counts, then cursor)
    int*   srcs   = cursor + N_NODES;                   // 800000
    float* vals   = (float*)(srcs + N_EDGES);           // 800000

    const int EB = (N_EDGES + 255) / 256;   // 3125

    hipMemsetAsync(cursor, 0, N_NODES * sizeof(int), stream);
    hist_kernel<<<EB, 256, 0, stream>>>(edst, cursor);
    scan_kernel<<<1, 256, 0, stream>>>(cursor, offs);
    hipMemsetAsync(cursor, 0, N_NODES * sizeof(int), stream);
    build_kernel<<<EB, 256, 0, stream>>>(esrc, edst, eval, offs, cursor, srcs, vals);

    gather_kernel<<<(N_NODES + 3) / 4, 256, 0, stream>>>(X, offs, srcs, vals, Y);

    dim3 grid((N_NODES + BM - 1) / BM, H_OUT / BN);
    gemm_relu_kernel<<<grid, 256, 0, stream>>>(Y, W, out);
}

// Round 3
// 385.207 us; speedup vs baseline: 14.6385x; 2.0433x over previous
//
#include <hip/hip_runtime.h>
#include <hip/hip_bf16.h>

#define N_NODES 50000
#define N_EDGES 800000
#define M_IN 512
#define H_OUT 512

typedef __attribute__((ext_vector_type(8))) short    bf16x8;  // MFMA A/B frag (4 VGPR)
typedef __attribute__((ext_vector_type(4))) float    f32x4;   // MFMA C/D frag
typedef __attribute__((ext_vector_type(8))) unsigned short u16x8;

__device__ inline float bf2f(unsigned short u) {
    unsigned int x = ((unsigned int)u) << 16;
    return __builtin_bit_cast(float, x);
}
__device__ inline unsigned short f2bf(float f) {   // round-to-nearest-even
    unsigned int x = __builtin_bit_cast(unsigned int, f);
    return (unsigned short)((x + 0x7FFF + ((x >> 16) & 1)) >> 16);
}
__device__ inline void gload_lds16(const void* g, void* lds) {
    __builtin_amdgcn_global_load_lds(
        (const __attribute__((address_space(1))) void*)g,
        (__attribute__((address_space(3))) void*)lds, 16, 0, 0);
}

// ---------------------------------------------------------------------------
// dtype conversions
// ---------------------------------------------------------------------------
__global__ __launch_bounds__(256) void convx_kernel(
    const float* __restrict__ X, unsigned short* __restrict__ Xb)
{
    const size_t i = (size_t)blockIdx.x * 256 + threadIdx.x;   // 3.2M threads, 8 f32 each
    const float4 a = ((const float4*)X)[2 * i];
    const float4 b = ((const float4*)X)[2 * i + 1];
    u16x8 o;
    o[0] = f2bf(a.x); o[1] = f2bf(a.y); o[2] = f2bf(a.z); o[3] = f2bf(a.w);
    o[4] = f2bf(b.x); o[5] = f2bf(b.y); o[6] = f2bf(b.z); o[7] = f2bf(b.w);
    *(u16x8*)(Xb + i * 8) = o;
}

// Wt[n][k] = bf16(W[k][n]) — 0.5 MB, L2-resident
__global__ __launch_bounds__(256) void convw_kernel(
    const float* __restrict__ W, unsigned short* __restrict__ Wt)
{
    const int id = blockIdx.x * 256 + threadIdx.x;   // 262144
    const int n = id >> 9, k = id & 511;
    Wt[(size_t)n * 512 + k] = f2bf(W[(size_t)k * 512 + n]);
}

// ---------------------------------------------------------------------------
// CSR build (unchanged from round 2)
// ---------------------------------------------------------------------------
__global__ __launch_bounds__(256) void hist_kernel(
    const int* __restrict__ edst, int* __restrict__ counts)
{
    const int e = blockIdx.x * 256 + threadIdx.x;
    if (e < N_EDGES) atomicAdd(&counts[edst[e]], 1);
}

__global__ __launch_bounds__(256) void scan_kernel(
    const int* __restrict__ counts, int* __restrict__ offs)
{
    __shared__ int psum[256];
    const int tid = threadIdx.x;
    const int CH  = (N_NODES + 255) / 256;
    const int b   = tid * CH;
    const int e   = min(b + CH, N_NODES);
    int s = 0;
    for (int i = b; i < e; ++i) s += counts[i];
    psum[tid] = s;
    __syncthreads();
    if (tid == 0) {
        int run = 0;
        for (int i = 0; i < 256; ++i) { int t = psum[i]; psum[i] = run; run += t; }
    }
    __syncthreads();
    int run = psum[tid];
    for (int i = b; i < e; ++i) { offs[i] = run; run += counts[i]; }
    if (e == N_NODES) offs[N_NODES] = run;
}

__global__ __launch_bounds__(256) void build_kernel(
    const int* __restrict__ esrc, const int* __restrict__ edst,
    const float* __restrict__ eval,
    const int* __restrict__ offs, int* __restrict__ cursor,
    int* __restrict__ srcs, float* __restrict__ vals)
{
    const int e = blockIdx.x * 256 + threadIdx.x;
    if (e >= N_EDGES) return;
    const int d   = edst[e];
    const int pos = offs[d] + atomicAdd(&cursor[d], 1);
    srcs[pos] = esrc[e];
    vals[pos] = eval[e];
}

// ---------------------------------------------------------------------------
// Gather (bf16 in / fp32 accum / bf16 out): one wave per dst node.
// One global_load_dwordx4 per lane per edge (8 bf16), row written once.
// ---------------------------------------------------------------------------
__global__ __launch_bounds__(256) void gather_kernel(
    const unsigned short* __restrict__ Xb,
    const int*   __restrict__ offs,
    const int*   __restrict__ srcs,
    const float* __restrict__ vals,
    unsigned short* __restrict__ Yb)
{
    const int node = blockIdx.x * 4 + (threadIdx.x >> 6);
    const int lane = threadIdx.x & 63;
    if (node >= N_NODES) return;

    const int beg = offs[node];
    const int end = offs[node + 1];

    float acc[8] = {};

    int e = beg;
    for (; e + 1 < end; e += 2) {
        const int   s0 = srcs[e],   s1 = srcs[e + 1];
        const float v0 = vals[e],   v1 = vals[e + 1];
        const u16x8 p = *(const u16x8*)(Xb + (size_t)s0 * M_IN + lane * 8);
        const u16x8 q = *(const u16x8*)(Xb + (size_t)s1 * M_IN + lane * 8);
#pragma unroll
        for (int j = 0; j < 8; ++j)
            acc[j] += bf2f(p[j]) * v0 + bf2f(q[j]) * v1;
    }
    if (e < end) {
        const int   s0 = srcs[e];
        const float v0 = vals[e];
        const u16x8 p = *(const u16x8*)(Xb + (size_t)s0 * M_IN + lane * 8);
#pragma unroll
        for (int j = 0; j < 8; ++j)
            acc[j] += bf2f(p[j]) * v0;
    }

    u16x8 o;
#pragma unroll
    for (int j = 0; j < 8; ++j) o[j] = f2bf(acc[j]);
    *(u16x8*)(Yb + (size_t)node * M_IN + lane * 8) = o;
}

// ---------------------------------------------------------------------------
// out = relu(Yb @ Wt^T) — bf16 MFMA 16x16x32, fp32 accum.
// 128x128 tile, BK=32, 4 waves (2x2), 64x64 per wave, m97-style staging.
// LDS tiles [128 rows][32 k] bf16, 16B-chunk XOR swizzle: chunk ^= (row>>1)&3
// (pre-swizzled global source + swizzled ds_read; gload_lds dest stays linear).
// ---------------------------------------------------------------------------
#define BM 128
#define BN 128
#define BK 32

__global__ __launch_bounds__(256, 2) void gemm_mfma_kernel(
    const unsigned short* __restrict__ Yb,
    const unsigned short* __restrict__ Wt,
    float* __restrict__ out)
{
    __shared__ unsigned short As[BM * BK];  // 8 KB
    __shared__ unsigned short Bs[BN * BK];  // 8 KB

    const int tid  = threadIdx.x;
    const int lane = tid & 63;
    const int wid  = tid >> 6;
    const int wr   = wid >> 1;       // wave row 0..1
    const int wc   = wid & 1;        // wave col 0..1
    const int row0 = blockIdx.x * BM;
    const int col0 = blockIdx.y * BN;

    f32x4 acc[4][4] = {};

    // per-thread staging geometry (2 16B chunks each for A and B)
    int srow[2], ksw[2], ldsb[2];
#pragma unroll
    for (int i = 0; i < 2; ++i) {
        const int b    = (i * 256 + tid) * 16;      // linear byte in 8 KB tile
        const int row  = b >> 6;                    // tile row (64 B per row)
        const int cir  = (b >> 4) & 3;              // 16B chunk within row
        srow[i] = row;
        ksw[i]  = (cir ^ ((row >> 1) & 3)) << 3;    // swizzled k element offset
        ldsb[i] = b;
    }

    // ds_read addresses (logical chunk c = lane>>4, swizzled)
    int abyte[4], bbyte[4];
    const int c = lane >> 4;
#pragma unroll
    for (int m = 0; m < 4; ++m) {
        const int ra = wr * 64 + m * 16 + (lane & 15);
        abyte[m] = ra * 64 + ((c ^ ((ra >> 1) & 3)) << 4);
        const int rb = wc * 64 + m * 16 + (lane & 15);
        bbyte[m] = rb * 64 + ((c ^ ((rb >> 1) & 3)) << 4);
    }

    for (int k0 = 0; k0 < M_IN; k0 += BK) {
#pragma unroll
        for (int i = 0; i < 2; ++i) {
            int gr = row0 + srow[i];
            if (gr >= N_NODES) gr = N_NODES - 1;    // clamp (rows not stored)
            gload_lds16(Yb + (size_t)gr * M_IN + k0 + ksw[i], (char*)As + ldsb[i]);
            gload_lds16(Wt + (size_t)(col0 + srow[i]) * M_IN + k0 + ksw[i], (char*)Bs + ldsb[i]);
        }
        __syncthreads();   // drains vmcnt before ds_read

        bf16x8 af[4], bfr[4];
#pragma unroll
        for (int m = 0; m < 4; ++m) af[m]  = *(const bf16x8*)((const char*)As + abyte[m]);
#pragma unroll
        for (int n = 0; n < 4; ++n) bfr[n] = *(const bf16x8*)((const char*)Bs + bbyte[n]);

#pragma unroll
        for (int m = 0; m < 4; ++m)
#pragma unroll
            for (int n = 0; n < 4; ++n)
                acc[m][n] = __builtin_amdgcn_mfma_f32_16x16x32_bf16(
                    af[m], bfr[n], acc[m][n], 0, 0, 0);

        __syncthreads();   // before next staging overwrite
    }

    // epilogue: C/D map col=lane&15, row=(lane>>4)*4+r  [measured m89]
#pragma unroll
    for (int m = 0; m < 4; ++m) {
#pragma unroll
        for (int n = 0; n < 4; ++n) {
#pragma unroll
            for (int r = 0; r < 4; ++r) {
                const int row = row0 + wr * 64 + m * 16 + (lane >> 4) * 4 + r;
                const int col = col0 + wc * 64 + n * 16 + (lane & 15);
                if (row < N_NODES)
                    out[(size_t)row * H_OUT + col] = fmaxf(acc[m][n][r], 0.f);
            }
        }
    }
}

extern "C" void kernel_launch(void* const* d_in, const int* in_sizes, int n_in,
                              void* d_out, int out_size, void* d_ws, size_t ws_size,
                              hipStream_t stream) {
    const float* X    = (const float*)d_in[0];
    const float* W    = (const float*)d_in[1];
    const int*   esrc = (const int*)d_in[2];
    const int*   edst = (const int*)d_in[3];
    const float* eval = (const float*)d_in[4];
    float* out = (float*)d_out;

    // workspace layout (bytes, all 16B-aligned)
    char* w = (char*)d_ws;
    unsigned short* Yb = (unsigned short*)w;  w += (size_t)N_NODES * M_IN * 2;  // 51.2 MB
    unsigned short* Xb = (unsigned short*)w;  w += (size_t)N_NODES * M_IN * 2;  // 51.2 MB
    unsigned short* Wt = (unsigned short*)w;  w += (size_t)M_IN * H_OUT * 2;    // 0.5 MB
    int*   offs   = (int*)w;                  w += (size_t)(N_NODES + 1) * 4;
    int*   cursor = (int*)w;                  w += (size_t)N_NODES * 4;
    int*   srcs   = (int*)w;                  w += (size_t)N_EDGES * 4;
    float* vals   = (float*)w;

    const int EB = (N_EDGES + 255) / 256;

    convx_kernel<<<12500, 256, 0, stream>>>(X, Xb);
    convw_kernel<<<1024, 256, 0, stream>>>(W, Wt);

    hipMemsetAsync(cursor, 0, N_NODES * sizeof(int), stream);
    hist_kernel<<<EB, 256, 0, stream>>>(edst, cursor);
    scan_kernel<<<1, 256, 0, stream>>>(cursor, offs);
    hipMemsetAsync(cursor, 0, N_NODES * sizeof(int), stream);
    build_kernel<<<EB, 256, 0, stream>>>(esrc, edst, eval, offs, cursor, srcs, vals);

    gather_kernel<<<(N_NODES + 3) / 4, 256, 0, stream>>>(Xb, offs, srcs, vals, Yb);

    dim3 grid((N_NODES + BM - 1) / BM, H_OUT / BN);
    gemm_mfma_kernel<<<grid, 256, 0, stream>>>(Yb, Wt, out);
}